// Round 5
// baseline (530.800 us; speedup 1.0000x reference)
//
#include <hip/hip_runtime.h>

#define NTHR 256

typedef __bf16 bf16x8 __attribute__((ext_vector_type(8)));
typedef float  f32x4  __attribute__((ext_vector_type(4)));
typedef unsigned long long u64;

__device__ __forceinline__ unsigned short f2bf(float f) {
  unsigned int u = __float_as_uint(f);
  return (unsigned short)((u + 0x7fffu + ((u >> 16) & 1u)) >> 16);  // RNE
}
__device__ __forceinline__ bf16x8 asbf(uint4 u) { return __builtin_bit_cast(bf16x8, u); }
__device__ __forceinline__ uint4 mk4(u64 lo, u64 hi) {
  uint2 l = __builtin_bit_cast(uint2, lo), h = __builtin_bit_cast(uint2, hi);
  return make_uint4(l.x, l.y, h.x, h.y);
}
__device__ __forceinline__ float sigf(float xv) { return 1.0f / (1.0f + __expf(-xv)); }

// --- cross-XCD primitives (proven rounds 3/4) ---
template <typename T>
__device__ __forceinline__ T ald(const T* p) {
  return __hip_atomic_load(p, __ATOMIC_RELAXED, __HIP_MEMORY_SCOPE_AGENT);
}
template <typename T>
__device__ __forceinline__ void xst(T* p, T v) {
  (void)__hip_atomic_exchange(p, v, __ATOMIC_RELAXED, __HIP_MEMORY_SCOPE_AGENT);
}

// ws layout (bytes):
//   OUTB bf16 [2][32][1024]     parity ping-pong of cell input   131072
//   HBB  bf16 [2][2][32][1024]  [t-parity][layer] h for GEMM     262144
//   CNT  int  [32][16] slots, 256B-strided (64-int)              131072
//   BCB  f32  [2][4096]         combined bias                     32768
//   SSE  f32
#define WS_OUTB 0
#define WS_HBB  131072
#define WS_CNT  (WS_HBB + 262144)
#define WS_BCB  (WS_CNT + 131072)
#define WS_SSE  (WS_BCB + 32768)

// ---------------- prep: state init only ----------------
__global__ void prep_kernel(const float* __restrict__ x, const float* __restrict__ h0,
                            const float* __restrict__ bih, const float* __restrict__ bhh,
                            unsigned char* __restrict__ ws)
{
  unsigned short* outb = (unsigned short*)(ws + WS_OUTB);
  unsigned short* hbb  = (unsigned short*)(ws + WS_HBB);
  int*   cnt = (int*)(ws + WS_CNT);
  float* bcb = (float*)(ws + WS_BCB);
  float* sse = (float*)(ws + WS_SSE);

  int gid = blockIdx.x * blockDim.x + threadIdx.x;
  int stride = gridDim.x * blockDim.x;

  for (int i = gid; i < 32768; i += stride) outb[i] = f2bf(x[i]);   // parity 0 = x
  for (int i = gid; i < 65536; i += stride) hbb[i] = f2bf(h0[i]);   // t-parity 0, both layers
  for (int i = gid; i < 8192; i += stride) bcb[i] = bih[i] + bhh[i];
  for (int i = gid; i < 32768; i += stride) cnt[i] = 0;
  if (gid == 0) *sse = 0.0f;
}

// ---------------- one cell inside the persistent kernel ----------------
// Block bid owns 4 h-columns (bid*4..+4) x all 4 gates, FULL K=2048.
// Wave w = K-quarter: w<2 -> x-part (outb), w>=2 -> h-part (hbb, data from ci-2:
//   already complete when the block enters this cell -> no poll, overlaps the x-wait).
// K-reduction is intra-block via LDS Cred (parity-double-buffered); summation
// order (quarter 0,1,2,3) is bit-identical to the split-K-across-blocks version.
template <int L>
__device__ __forceinline__ void cell_step(
    int t, const uint4 (&wreg)[16],
    const float* __restrict__ hmask, const float* __restrict__ cmask,
    const float* __restrict__ labels, const float2 (&bv)[4],
    float2& cS, float2& hS,
    float* __restrict__ out, unsigned char* __restrict__ ws,
    float* __restrict__ CredBase)
{
  const int tid = threadIdx.x, bid = blockIdx.x;
  const int lane = tid & 63, w = tid >> 6, q = lane >> 4, m0 = lane & 15;
  const int ci = t * 2 + L;

  unsigned short* outb = (unsigned short*)(ws + WS_OUTB);
  unsigned short* hbb  = (unsigned short*)(ws + WS_HBB);
  int*   cnt = (int*)(ws + WS_CNT);
  float* sse = (float*)(ws + WS_SSE);

  // pointwise geometry (wave 0 only): 1 batch row x 2 adjacent cols
  const int mr = tid >> 1, cp = tid & 1, col = bid * 4 + cp * 2;

  // read-only prefetch (immutable; plain cached loads; hides under the spin)
  float2 hm = make_float2(0.f, 0.f), cm = hm, lb = hm;
  if (tid < 64) {
    const int mbase = ci * 32768 + mr * 1024 + col;
    hm = *(const float2*)&hmask[mbase];
    cm = *(const float2*)&cmask[mbase];
    if (L == 1) lb = *(const float2*)&labels[(mr * 16 + t) * 1024 + col];
  }

  // --- grid gate: only x-waves poll (16 lanes, 16 sharded slots) ---
  if (ci > 0 && w < 2) {
    if (lane < 16) {
      while (ald(cnt + ((size_t)(ci - 1) * 16 + lane) * 64) < 16)
        __builtin_amdgcn_s_sleep(1);
    }
  }

  // --- A-fragments DIRECT from global (no LDS staging): 64 x 8B agent loads,
  //     one latency exposure. Each 16B chunk is consumed by exactly one lane. ---
  const unsigned short* asrc = (w < 2) ? (outb + L * 32768)
                                       : (hbb + ((t & 1) * 2 + L) * 32768);
  const int koff = (w & 1) * 512 + q * 8;
  u64 alo[16], ahi[16], clo[16], chi[16];
#pragma unroll
  for (int ks = 0; ks < 16; ++ks) {
    const unsigned short* p0 = asrc + m0 * 1024 + koff + ks * 32;
    const unsigned short* p1 = p0 + 16 * 1024;
    alo[ks] = ald((const u64*)p0); ahi[ks] = ald((const u64*)(p0 + 4));
    clo[ks] = ald((const u64*)p1); chi[ks] = ald((const u64*)(p1 + 4));
  }

  // --- MFMA: quarter-K chain, weights resident in registers ---
  f32x4 acc0 = {0.f, 0.f, 0.f, 0.f}, acc1 = {0.f, 0.f, 0.f, 0.f};
#pragma unroll
  for (int ks = 0; ks < 16; ++ks) {
    bf16x8 a0 = asbf(mk4(alo[ks], ahi[ks]));
    bf16x8 a1 = asbf(mk4(clo[ks], chi[ks]));
    bf16x8 b  = asbf(wreg[ks]);
    acc0 = __builtin_amdgcn_mfma_f32_16x16x32_bf16(a0, b, acc0, 0, 0, 0);
    acc1 = __builtin_amdgcn_mfma_f32_16x16x32_bf16(a1, b, acc1, 0, 0, 0);
  }

  // --- intra-block K-reduce via LDS, parity-buffered (Cred[2][4][32][17]) ---
  float* credp = CredBase + (ci & 1) * (4 * 32 * 17);
  float* cw = credp + w * (32 * 17);
#pragma unroll
  for (int i = 0; i < 4; ++i) {
    cw[(q * 4 + i) * 17 + m0]      = acc0[i];   // C/D: m = q*4+i, n = m0
    cw[(q * 4 + i + 16) * 17 + m0] = acc1[i];
  }

  __syncthreads();   // the ONLY block barrier per cell: Cred writes -> wave-0 reads

  if (tid < 64) {
    // n-index = gt*4 + cc  ->  row = gt*1024 + bid*4 + cc  (gate-complete columns)
    float gx[4], gy[4];
#pragma unroll
    for (int gt = 0; gt < 4; ++gt) {
      float s0 = bv[gt].x, s1 = bv[gt].y;
#pragma unroll
      for (int w4 = 0; w4 < 4; ++w4) {
        const float* cr = credp + w4 * (32 * 17) + mr * 17 + gt * 4 + cp * 2;
        s0 += cr[0]; s1 += cr[1];
      }
      gx[gt] = s0; gy[gt] = s1;
    }
    float i0 = sigf(gx[0]), f0 = sigf(gx[1]), g0 = tanhf(gx[2]), o0 = sigf(gx[3]);
    float i1 = sigf(gy[0]), f1 = sigf(gy[1]), g1 = tanhf(gy[2]), o1 = sigf(gy[3]);
    float cc0 = f0 * cS.x + i0 * g0, cc1 = f1 * cS.y + i1 * g1;
    float hc0 = o0 * tanhf(cc0),     hc1 = o1 * tanhf(cc1);
    float hn0 = hm.x * hS.x + (1.0f - hm.x) * hc0;
    float hn1 = hm.y * hS.y + (1.0f - hm.y) * hc1;
    float cn0 = cm.x * cS.x + (1.0f - cm.x) * cc0;
    float cn1 = cm.y * cS.y + (1.0f - cm.y) * cc1;
    cS = make_float2(cn0, cn1);          // block-private fp32 state stays in regs
    hS = make_float2(hn0, hn1);

    const unsigned int hb = (unsigned int)f2bf(hn0) | ((unsigned int)f2bf(hn1) << 16);
    xst((unsigned int*)&outb[(L ^ 1) * 32768 + mr * 1024 + col], hb);
    xst((unsigned int*)&hbb[(((t + 1) & 1) * 2 + L) * 32768 + mr * 1024 + col], hb);

    if (L == 1) {
      *(float2*)&out[(mr * 16 + t) * 1024 + col] = make_float2(hn0, hn1);
      float d0 = hn0 - lb.x, d1 = hn1 - lb.y;
      float s = d0 * d0 + d1 * d1;
#pragma unroll
      for (int off = 32; off > 0; off >>= 1) s += __shfl_down(s, off);
      if (lane == 0) atomicAdd(sse, s);
    }
    // wave-local drain of the publishes, then signal
    asm volatile("s_waitcnt vmcnt(0)" ::: "memory");
  }
  if (tid == 0)
    __hip_atomic_fetch_add(cnt + ((size_t)ci * 16 + (bid & 15)) * 64, 1,
                           __ATOMIC_RELAXED, __HIP_MEMORY_SCOPE_AGENT);
}

// ---------------- persistent kernel: weights in registers, 32 cells in-kernel ----
// grid = 256 blocks (1/CU). Block owns 4 h-cols x 4 gates, full K.
__global__ void __launch_bounds__(NTHR, 1)
lstm_kernel(const float* __restrict__ Wih, const float* __restrict__ Whh,
            const float* __restrict__ h0c, const float* __restrict__ c0c,
            const float* __restrict__ hmask, const float* __restrict__ cmask,
            const float* __restrict__ labels, float* __restrict__ out,
            unsigned char* __restrict__ ws)
{
  const int tid = threadIdx.x, bid = blockIdx.x;
  const int lane = tid & 63, w = tid >> 6, q = lane >> 4, m0 = lane & 15;

  __shared__ __align__(16) float Cred[2][4][32][17];   // 17.4 KB

  // ---- one-time: fp32 weights -> bf16 registers (128 VGPRs, both layers) ----
  // lane n=m0 -> weight row = (m0>>2)*1024 + bid*4 + (m0&3) (gate, col)
  // wave w -> K-quarter: w<2 from Wih, w>=2 from Whh; kc = (w&1)*512 + q*8 + ks*32
  uint4 w0r[16], w1r[16];
  {
    const size_t row = (size_t)((m0 >> 2) * 1024 + bid * 4 + (m0 & 3));
    const float* b0 = ((w < 2) ? Wih : Whh) + row * 1024 + (w & 1) * 512 + q * 8;
    const float* b1 = b0 + 4194304;   // layer 1: +4096*1024 floats
#pragma unroll
    for (int ks = 0; ks < 16; ++ks) {
      float4 a = *(const float4*)(b0 + ks * 32), b = *(const float4*)(b0 + ks * 32 + 4);
      w0r[ks].x = (unsigned int)f2bf(a.x) | ((unsigned int)f2bf(a.y) << 16);
      w0r[ks].y = (unsigned int)f2bf(a.z) | ((unsigned int)f2bf(a.w) << 16);
      w0r[ks].z = (unsigned int)f2bf(b.x) | ((unsigned int)f2bf(b.y) << 16);
      w0r[ks].w = (unsigned int)f2bf(b.z) | ((unsigned int)f2bf(b.w) << 16);
      float4 c = *(const float4*)(b1 + ks * 32), d = *(const float4*)(b1 + ks * 32 + 4);
      w1r[ks].x = (unsigned int)f2bf(c.x) | ((unsigned int)f2bf(c.y) << 16);
      w1r[ks].y = (unsigned int)f2bf(c.z) | ((unsigned int)f2bf(c.w) << 16);
      w1r[ks].z = (unsigned int)f2bf(d.x) | ((unsigned int)f2bf(d.y) << 16);
      w1r[ks].w = (unsigned int)f2bf(d.z) | ((unsigned int)f2bf(d.w) << 16);
    }
  }

  // ---- block-private state + bias in registers (pointwise threads, wave 0) ----
  const int mr = tid >> 1, cp = tid & 1, col = bid * 4 + cp * 2;
  float2 cs0 = make_float2(0.f, 0.f), hs0 = cs0, cs1 = cs0, hs1 = cs0;
  float2 bv0[4], bv1[4];
#pragma unroll
  for (int gt = 0; gt < 4; ++gt) { bv0[gt] = make_float2(0.f, 0.f); bv1[gt] = bv0[gt]; }
  if (tid < 64) {
    const float* bcb = (const float*)(ws + WS_BCB);
#pragma unroll
    for (int gt = 0; gt < 4; ++gt) {
      bv0[gt] = *(const float2*)&bcb[gt * 1024 + col];
      bv1[gt] = *(const float2*)&bcb[4096 + gt * 1024 + col];
    }
    cs0 = *(const float2*)&c0c[mr * 1024 + col];
    cs1 = *(const float2*)&c0c[32768 + mr * 1024 + col];
    hs0 = *(const float2*)&h0c[mr * 1024 + col];
    hs1 = *(const float2*)&h0c[32768 + mr * 1024 + col];
  }

#pragma unroll 1
  for (int t = 0; t < 16; ++t) {
    cell_step<0>(t, w0r, hmask, cmask, labels, bv0, cs0, hs0, out, ws, &Cred[0][0][0][0]);
    cell_step<1>(t, w1r, hmask, cmask, labels, bv1, cs1, hs1, out, ws, &Cred[0][0][0][0]);
  }
}

// ---------------- finalize: loss ----------------
__global__ void fin_kernel(float* __restrict__ out, unsigned char* __restrict__ ws) {
  if (blockIdx.x == 0 && threadIdx.x == 0)
    out[524288] = *(float*)(ws + WS_SSE) * (1.0f / 524288.0f);
}

extern "C" void kernel_launch(void* const* d_in, const int* in_sizes, int n_in,
                              void* d_out, int out_size, void* d_ws, size_t ws_size,
                              hipStream_t stream) {
  (void)in_sizes; (void)n_in; (void)out_size; (void)ws_size;
  const float* x   = (const float*)d_in[0];
  const float* h0  = (const float*)d_in[1];
  const float* c0  = (const float*)d_in[2];
  const float* hm  = (const float*)d_in[3];
  const float* cm  = (const float*)d_in[4];
  const float* lb  = (const float*)d_in[5];
  const float* wih = (const float*)d_in[6];
  const float* whh = (const float*)d_in[7];
  const float* bi  = (const float*)d_in[8];
  const float* bh  = (const float*)d_in[9];
  float* out = (float*)d_out;
  unsigned char* ws = (unsigned char*)d_ws;

  prep_kernel<<<dim3(256), dim3(256), 0, stream>>>(x, h0, bi, bh, ws);
  lstm_kernel<<<dim3(256), dim3(NTHR), 0, stream>>>(wih, whh, h0, c0, hm, cm, lb, out, ws);
  fin_kernel<<<dim3(1), dim3(64), 0, stream>>>(out, ws);
}

// Round 6
// 382.501 us; speedup vs baseline: 1.3877x; 1.3877x over previous
//
#include <hip/hip_runtime.h>

#define NTHR 512

typedef __bf16 bf16x8 __attribute__((ext_vector_type(8)));
typedef float  f32x4  __attribute__((ext_vector_type(4)));
typedef unsigned long long u64;

__device__ __forceinline__ unsigned short f2bf(float f) {
  unsigned int u = __float_as_uint(f);
  return (unsigned short)((u + 0x7fffu + ((u >> 16) & 1u)) >> 16);  // RNE
}
__device__ __forceinline__ bf16x8 asbf(uint4 u) { return __builtin_bit_cast(bf16x8, u); }
__device__ __forceinline__ uint4 mk4(u64 lo, u64 hi) {
  uint2 l = __builtin_bit_cast(uint2, lo), h = __builtin_bit_cast(uint2, hi);
  return make_uint4(l.x, l.y, h.x, h.y);
}
__device__ __forceinline__ float sigf(float xv) { return 1.0f / (1.0f + __expf(-xv)); }

// --- cross-XCD primitives (proven rounds 3-5) ---
template <typename T>
__device__ __forceinline__ T ald(const T* p) {
  return __hip_atomic_load(p, __ATOMIC_RELAXED, __HIP_MEMORY_SCOPE_AGENT);
}
template <typename T>
__device__ __forceinline__ void xst(T* p, T v) {
  (void)__hip_atomic_exchange(p, v, __ATOMIC_RELAXED, __HIP_MEMORY_SCOPE_AGENT);
}
__device__ __forceinline__ u64 pkf2(float a, float b) {
  float2 f = make_float2(a, b);
  return __builtin_bit_cast(u64, f);
}

// ws layout (bytes):
//   OUTB bf16 [2][32][1024]          layer-indexed cell input          131072
//   HBB  bf16 [2][2][32][1024]       [t-parity][layer] h for GEMM      262144
//   XFLG int  [32][128] x64B stride  per-cell per-xblock done tags     262144
//   HFLG int  [32][128] x64B stride  per-cell per-hblock Ps-ready      262144
//   PS   f32  [2][2][128][32][32]    [t-par][L][g] h-GEMM partials    2097152
//   BCB  f32  [2][4096]              combined bias                      32768
//   SSE  f32
#define WS_OUTB 0
#define WS_HBB  131072
#define WS_XFLG 393216
#define WS_HFLG 655360
#define WS_PS   917504
#define WS_BCB  3014656
#define WS_SSE  3047424

// ---------------- prep ----------------
__global__ void prep_kernel(const float* __restrict__ x, const float* __restrict__ h0,
                            const float* __restrict__ bih, const float* __restrict__ bhh,
                            unsigned char* __restrict__ ws)
{
  unsigned short* outb = (unsigned short*)(ws + WS_OUTB);
  unsigned short* hbb  = (unsigned short*)(ws + WS_HBB);
  int*   flg = (int*)(ws + WS_XFLG);     // covers XFLG+HFLG contiguously
  float* bcb = (float*)(ws + WS_BCB);
  float* sse = (float*)(ws + WS_SSE);

  int gid = blockIdx.x * blockDim.x + threadIdx.x;
  int stride = gridDim.x * blockDim.x;

  for (int i = gid; i < 32768; i += stride) outb[i] = f2bf(x[i]);   // input of cell 0
  for (int i = gid; i < 65536; i += stride) hbb[i] = f2bf(h0[i]);   // t-parity 0, both layers
  for (int i = gid; i < 8192; i += stride) bcb[i] = bih[i] + bhh[i];
  for (int i = gid; i < 131072; i += stride) flg[i] = 0;            // xflg + hflg
  if (gid == 0) *sse = 0.0f;
}

// ---------------- persistent kernel ----------------
// 256 blocks x 512 threads. g = bid>>1 owns 8 h-columns (both layers);
// role = bid&1: 0 = x-block (W_ih GEMM + pointwise + state, critical path),
//               1 = h-block (W_hh GEMM, input from ci-2 -> runs shadowed one
//                   cell early, publishes pre-reduced 4KB partial).
// Waves: w = (kh<<2)|(nt<<1)|mt; each wave one 16x16 C-tile, K=512 chain.
// LDS sized ~93KB -> 1 block/CU forced -> all 256 blocks co-resident.
__global__ void __launch_bounds__(NTHR, 1)
lstm_kernel(const float* __restrict__ Wih, const float* __restrict__ Whh,
            const float* __restrict__ h0c, const float* __restrict__ c0c,
            const float* __restrict__ hmask, const float* __restrict__ cmask,
            const float* __restrict__ labels, float* __restrict__ out,
            unsigned char* __restrict__ ws)
{
  const int tid = threadIdx.x, bid = blockIdx.x;
  const int g = bid >> 1, role = bid & 1;
  const int lane = tid & 63, w = tid >> 6;
  const int mt = w & 1, nt = (w >> 1) & 1, kh = w >> 2;
  const int q = lane >> 4, m0 = lane & 15;

  // As rows 32..40 unused: pads LDS past 80KB to force 1 block/CU.
  __shared__ __align__(16) unsigned short As[41 * 1032];   // 84.6 KB (stride 1032)
  __shared__ __align__(16) float Cred[2][32][36];          // 9.2 KB

  unsigned short* outb = (unsigned short*)(ws + WS_OUTB);
  unsigned short* hbb  = (unsigned short*)(ws + WS_HBB);
  int*   xflg = (int*)(ws + WS_XFLG);
  int*   hflg = (int*)(ws + WS_HFLG);
  float* PsF  = (float*)(ws + WS_PS);
  const float* bcb = (const float*)(ws + WS_BCB);
  float* sse = (float*)(ws + WS_SSE);

  // ---- one-time: fp32 weights -> bf16 registers (128 VGPRs, both layers) ----
  // wave-tile n = nt*16 + m0 -> weight row = (n>>3)*1024 + g*8 + (n&7)
  // K per wave = kh*512 .. +512; fragment k = kbase + ks*32 (8 floats)
  uint4 w0r[16], w1r[16];
  {
    const int nloc = nt * 16 + m0;
    const size_t wrow = (size_t)((nloc >> 3) * 1024 + g * 8 + (nloc & 7));
    const int kbase = kh * 512 + q * 8;
    const float* b0 = (role ? Whh : Wih) + wrow * 1024 + kbase;
    const float* b1 = b0 + 4194304;   // layer 1
#pragma unroll
    for (int ks = 0; ks < 16; ++ks) {
      float4 a = *(const float4*)(b0 + ks * 32), b = *(const float4*)(b0 + ks * 32 + 4);
      w0r[ks].x = (unsigned int)f2bf(a.x) | ((unsigned int)f2bf(a.y) << 16);
      w0r[ks].y = (unsigned int)f2bf(a.z) | ((unsigned int)f2bf(a.w) << 16);
      w0r[ks].z = (unsigned int)f2bf(b.x) | ((unsigned int)f2bf(b.y) << 16);
      w0r[ks].w = (unsigned int)f2bf(b.z) | ((unsigned int)f2bf(b.w) << 16);
      float4 c = *(const float4*)(b1 + ks * 32), d = *(const float4*)(b1 + ks * 32 + 4);
      w1r[ks].x = (unsigned int)f2bf(c.x) | ((unsigned int)f2bf(c.y) << 16);
      w1r[ks].y = (unsigned int)f2bf(c.z) | ((unsigned int)f2bf(c.w) << 16);
      w1r[ks].z = (unsigned int)f2bf(d.x) | ((unsigned int)f2bf(d.y) << 16);
      w1r[ks].w = (unsigned int)f2bf(d.z) | ((unsigned int)f2bf(d.w) << 16);
    }
  }

  // ---- x-block per-thread pointwise geometry, state + bias in registers ----
  const int m = tid >> 3, jc = tid & 7, col = g * 8 + jc;   // valid for tid<256
  float cs0 = 0.f, hs0 = 0.f, cs1 = 0.f, hs1 = 0.f;
  float bv0[4] = {0, 0, 0, 0}, bv1[4] = {0, 0, 0, 0};
  if (role == 0 && tid < 256) {
    cs0 = c0c[m * 1024 + col];           hs0 = h0c[m * 1024 + col];
    cs1 = c0c[32768 + m * 1024 + col];   hs1 = h0c[32768 + m * 1024 + col];
#pragma unroll
    for (int gt = 0; gt < 4; ++gt) {
      bv0[gt] = bcb[gt * 1024 + col];
      bv1[gt] = bcb[4096 + gt * 1024 + col];
    }
  }

#pragma unroll 1
  for (int ci = 0; ci < 32; ++ci) {
    const int t = ci >> 1, L = ci & 1;

    if (role == 0) {
      // ================= x-block: the critical path =================
      // prefetch masks/labels (immutable, plain cached; hides under poll)
      float hmv = 0.f, cmv = 0.f, lbv = 0.f;
      if (tid < 256) {
        const int mb = ci * 32768 + m * 1024 + col;
        hmv = hmask[mb]; cmv = cmask[mb];
        if (L == 1) lbv = labels[(m * 16 + t) * 1024 + col];
      }

      // poll: all 128 x-flags of ci-1 (input h), own h-flag of ci (partial)
      if (ci > 0 && tid < 128) {
        while (ald(&xflg[((ci - 1) * 128 + tid) * 16]) < ci)
          __builtin_amdgcn_s_sleep(1);
      }
      if (tid >= 128 && tid < 192) {
        while (ald(&hflg[(ci * 128 + g) * 16]) < ci + 1)
          __builtin_amdgcn_s_sleep(1);
      }
      __syncthreads();

      // h-GEMM partial (published early by h-block): 4 gate values / thread
      float psv[4];
      const float* psb = PsF + (size_t)(((t & 1) * 2 + L) * 128 + g) * 1024;
      if (tid < 256) {
#pragma unroll
        for (int gt = 0; gt < 4; ++gt)
          psv[gt] = ald(psb + m * 32 + gt * 8 + jc);
      }

      // stage outb[L] (32x1024 bf16, 64KB): 16 x 8B agent loads / thread
      const unsigned short* asrc = outb + L * 32768;
      u64 av[16];
#pragma unroll
      for (int it = 0; it < 16; ++it) {
        const int u = it * 512 + tid, row = u >> 8, c4 = u & 255;
        av[it] = ald((const u64*)(asrc + row * 1024 + c4 * 4));
      }
#pragma unroll
      for (int it = 0; it < 16; ++it) {
        const int u = it * 512 + tid, row = u >> 8, c4 = u & 255;
        *(u64*)&As[row * 1032 + c4 * 4] = av[it];
      }
      __syncthreads();

      // x-GEMM: wave tile (mt,nt), K = kh*512..+512 chained
      f32x4 acc = {0.f, 0.f, 0.f, 0.f};
#pragma unroll
      for (int ks = 0; ks < 16; ++ks) {
        const int kl = kh * 512 + ks * 32 + q * 8;
        bf16x8 a = asbf(*(const uint4*)&As[(mt * 16 + m0) * 1032 + kl]);
        bf16x8 b = asbf((L == 0) ? w0r[ks] : w1r[ks]);
        acc = __builtin_amdgcn_mfma_f32_16x16x32_bf16(a, b, acc, 0, 0, 0);
      }
#pragma unroll
      for (int i = 0; i < 4; ++i)
        Cred[kh][mt * 16 + q * 4 + i][nt * 16 + m0] = acc[i];
      __syncthreads();

      // pointwise: gate(m, n=gt*8+jc) = CredX[0]+CredX[1] + Ps + bias
      if (tid < 256) {
        float ga[4];
        if (L == 0) {
#pragma unroll
          for (int gt = 0; gt < 4; ++gt)
            ga[gt] = (Cred[0][m][gt * 8 + jc] + Cred[1][m][gt * 8 + jc]) + psv[gt] + bv0[gt];
        } else {
#pragma unroll
          for (int gt = 0; gt < 4; ++gt)
            ga[gt] = (Cred[0][m][gt * 8 + jc] + Cred[1][m][gt * 8 + jc]) + psv[gt] + bv1[gt];
        }
        const float cp = (L == 0) ? cs0 : cs1;
        const float hp = (L == 0) ? hs0 : hs1;
        const float ii = sigf(ga[0]), ff = sigf(ga[1]);
        const float gv = tanhf(ga[2]), oo = sigf(ga[3]);
        const float cc = ff * cp + ii * gv;
        const float hc = oo * tanhf(cc);
        const float hn = hmv * hp + (1.0f - hmv) * hc;
        const float cn = cmv * cp + (1.0f - cmv) * cc;
        if (L == 0) { cs0 = cn; hs0 = hn; } else { cs1 = cn; hs1 = hn; }

        // publish h as packed pairs (partner lane via shfl)
        const float hnp = __shfl_xor(hn, 1);
        if ((tid & 1) == 0) {
          const unsigned int hb =
              (unsigned int)f2bf(hn) | ((unsigned int)f2bf(hnp) << 16);
          xst((unsigned int*)&outb[(L ^ 1) * 32768 + m * 1024 + col], hb);
          xst((unsigned int*)&hbb[(((t + 1) & 1) * 2 + L) * 32768 + m * 1024 + col], hb);
        }
        if (L == 1) {
          out[(m * 16 + t) * 1024 + col] = hn;     // flushed at kernel end
          float d = hn - lbv;
          float s = d * d;
#pragma unroll
          for (int off = 32; off > 0; off >>= 1) s += __shfl_down(s, off);
          if ((tid & 63) == 0) atomicAdd(sse, s);
        }
      }
      __syncthreads();                 // per-wave vmcnt(0) drain of publishes
      if (tid == 0) xst(&xflg[(ci * 128 + g) * 16], ci + 1);

    } else {
      // ================= h-block: shadowed W_hh GEMM =================
      // input hbb[t&1][L] written at ci-2 -> gate on xflags(ci-2); by the
      // time we arrive this is almost always already set (2-cell lag).
      if (ci > 1 && tid < 128) {
        while (ald(&xflg[((ci - 2) * 128 + tid) * 16]) < ci - 1)
          __builtin_amdgcn_s_sleep(1);
      }
      __syncthreads();

      const unsigned short* asrc = hbb + ((t & 1) * 2 + L) * 32768;
      u64 av[16];
#pragma unroll
      for (int it = 0; it < 16; ++it) {
        const int u = it * 512 + tid, row = u >> 8, c4 = u & 255;
        av[it] = ald((const u64*)(asrc + row * 1024 + c4 * 4));
      }
#pragma unroll
      for (int it = 0; it < 16; ++it) {
        const int u = it * 512 + tid, row = u >> 8, c4 = u & 255;
        *(u64*)&As[row * 1032 + c4 * 4] = av[it];
      }
      __syncthreads();

      f32x4 acc = {0.f, 0.f, 0.f, 0.f};
#pragma unroll
      for (int ks = 0; ks < 16; ++ks) {
        const int kl = kh * 512 + ks * 32 + q * 8;
        bf16x8 a = asbf(*(const uint4*)&As[(mt * 16 + m0) * 1032 + kl]);
        bf16x8 b = asbf((L == 0) ? w0r[ks] : w1r[ks]);
        acc = __builtin_amdgcn_mfma_f32_16x16x32_bf16(a, b, acc, 0, 0, 0);
      }
#pragma unroll
      for (int i = 0; i < 4; ++i)
        Cred[kh][mt * 16 + q * 4 + i][nt * 16 + m0] = acc[i];
      __syncthreads();

      // kh-reduce + publish 4KB partial as 512 x 8B pairs
      {
        const int mH = tid >> 4, np = tid & 15;
        const float s0 = Cred[0][mH][2 * np]     + Cred[1][mH][2 * np];
        const float s1 = Cred[0][mH][2 * np + 1] + Cred[1][mH][2 * np + 1];
        float* psb = PsF + (size_t)(((t & 1) * 2 + L) * 128 + g) * 1024;
        xst((u64*)(psb + mH * 32 + 2 * np), pkf2(s0, s1));
      }
      __syncthreads();                 // drain Ps publishes
      if (tid == 0) xst(&hflg[(ci * 128 + g) * 16], ci + 1);
    }
  }
}

// ---------------- finalize: loss ----------------
__global__ void fin_kernel(float* __restrict__ out, unsigned char* __restrict__ ws) {
  if (blockIdx.x == 0 && threadIdx.x == 0)
    out[524288] = *(float*)(ws + WS_SSE) * (1.0f / 524288.0f);
}

extern "C" void kernel_launch(void* const* d_in, const int* in_sizes, int n_in,
                              void* d_out, int out_size, void* d_ws, size_t ws_size,
                              hipStream_t stream) {
  (void)in_sizes; (void)n_in; (void)out_size; (void)ws_size;
  const float* x   = (const float*)d_in[0];
  const float* h0  = (const float*)d_in[1];
  const float* c0  = (const float*)d_in[2];
  const float* hm  = (const float*)d_in[3];
  const float* cm  = (const float*)d_in[4];
  const float* lb  = (const float*)d_in[5];
  const float* wih = (const float*)d_in[6];
  const float* whh = (const float*)d_in[7];
  const float* bi  = (const float*)d_in[8];
  const float* bh  = (const float*)d_in[9];
  float* out = (float*)d_out;
  unsigned char* ws = (unsigned char*)d_ws;

  prep_kernel<<<dim3(256), dim3(256), 0, stream>>>(x, h0, bi, bh, ws);
  lstm_kernel<<<dim3(256), dim3(NTHR), 0, stream>>>(wih, whh, h0, c0, hm, cm, lb, out, ws);
  fin_kernel<<<dim3(1), dim3(64), 0, stream>>>(out, ws);
}

// Round 7
// 343.063 us; speedup vs baseline: 1.5472x; 1.1150x over previous
//
#include <hip/hip_runtime.h>

#define NTHR 512

typedef __bf16 bf16x8 __attribute__((ext_vector_type(8)));
typedef float  f32x4  __attribute__((ext_vector_type(4)));
typedef unsigned long long u64;

__device__ __forceinline__ unsigned short f2bf(float f) {
  unsigned int u = __float_as_uint(f);
  return (unsigned short)((u + 0x7fffu + ((u >> 16) & 1u)) >> 16);  // RNE
}
__device__ __forceinline__ bf16x8 asbf(uint4 u) { return __builtin_bit_cast(bf16x8, u); }
__device__ __forceinline__ float sigf(float xv) { return 1.0f / (1.0f + __expf(-xv)); }

// --- cross-XCD primitives (proven rounds 3-6) ---
template <typename T>
__device__ __forceinline__ T ald(const T* p) {
  return __hip_atomic_load(p, __ATOMIC_RELAXED, __HIP_MEMORY_SCOPE_AGENT);
}
template <typename T>
__device__ __forceinline__ void xst(T* p, T v) {
  (void)__hip_atomic_exchange(p, v, __ATOMIC_RELAXED, __HIP_MEMORY_SCOPE_AGENT);
}

// ws layout (bytes):
//   HOUT bf16 [L][tpar][32][1024]  published h (single destination)   262144
//   XIN  bf16 [32][1024]           f2bf(x), input of cell 0            65536
//   HI0  bf16 [32][1024]           f2bf(h0[L=0])                       65536
//   HI1  bf16 [32][1024]           f2bf(h0[L=1])                       65536
//   FLG  int  [32][128] x64B       per-cell per-group done tags       262144
//   BCB  f32  [2][4096]            combined bias                       32768
//   SSE  f32
#define WS_HOUT 0
#define WS_XIN  262144
#define WS_HI0  327680
#define WS_HI1  393216
#define WS_FLG  458752
#define WS_BCB  720896
#define WS_SSE  753664

// ---------------- prep ----------------
__global__ void prep_kernel(const float* __restrict__ x, const float* __restrict__ h0,
                            const float* __restrict__ bih, const float* __restrict__ bhh,
                            unsigned char* __restrict__ ws)
{
  unsigned short* xin = (unsigned short*)(ws + WS_XIN);
  unsigned short* hi0 = (unsigned short*)(ws + WS_HI0);
  unsigned short* hi1 = (unsigned short*)(ws + WS_HI1);
  int*   flg = (int*)(ws + WS_FLG);
  float* bcb = (float*)(ws + WS_BCB);
  float* sse = (float*)(ws + WS_SSE);

  int gid = blockIdx.x * blockDim.x + threadIdx.x;
  int stride = gridDim.x * blockDim.x;

  for (int i = gid; i < 32768; i += stride) xin[i] = f2bf(x[i]);
  for (int i = gid; i < 32768; i += stride) hi0[i] = f2bf(h0[i]);
  for (int i = gid; i < 32768; i += stride) hi1[i] = f2bf(h0[32768 + i]);
  for (int i = gid; i < 8192; i += stride) bcb[i] = bih[i] + bhh[i];
  for (int i = gid; i < 65536; i += stride) flg[i] = 0;
  if (gid == 0) *sse = 0.0f;
}

// ---- helpers (operate on the proven round-6 staging / MFMA patterns) ----
__device__ __forceinline__ void stage64k(const unsigned short* __restrict__ src,
                                         unsigned short* __restrict__ As, int tid) {
  u64 av[16];
#pragma unroll
  for (int it = 0; it < 16; ++it) {
    const int u = it * 512 + tid, row = u >> 8, c4 = u & 255;
    av[it] = ald((const u64*)(src + row * 1024 + c4 * 4));
  }
#pragma unroll
  for (int it = 0; it < 16; ++it) {
    const int u = it * 512 + tid, row = u >> 8, c4 = u & 255;
    *(u64*)&As[row * 1032 + c4 * 4] = av[it];
  }
}

__device__ __forceinline__ void gemm_to_cred(const uint4 (&wreg)[16],
                                             const unsigned short* __restrict__ As,
                                             float* __restrict__ Cred,
                                             int mt, int nt, int kh, int q, int m0) {
  f32x4 acc = {0.f, 0.f, 0.f, 0.f};
#pragma unroll
  for (int ks = 0; ks < 16; ++ks) {
    const int kl = kh * 512 + ks * 32 + q * 8;
    bf16x8 a = asbf(*(const uint4*)&As[(mt * 16 + m0) * 1032 + kl]);
    acc = __builtin_amdgcn_mfma_f32_16x16x32_bf16(a, asbf(wreg[ks]), acc, 0, 0, 0);
  }
#pragma unroll
  for (int i = 0; i < 4; ++i)
    Cred[kh * (32 * 36) + (mt * 16 + q * 4 + i) * 36 + nt * 16 + m0] = acc[i];
}

// ---------------- persistent kernel ----------------
// 256 blocks x 512 threads = 2 layers x 128 groups (8 h-columns each).
// Block (L,g): holds W_ih AND W_hh rows for its columns in registers (128 VGPR).
// Active on cells with ci&1==L: poll flags(ci-1) -> stage h(ci-1) -> x-GEMM ->
// pointwise using LOCAL h-partial (computed in the idle window from ci-2 data,
// kept in LDS) -> publish 2KB h -> flag. The h-GEMM never crosses blocks.
// LDS ~98KB forces 1 block/CU -> all 256 blocks co-resident.
__global__ void __launch_bounds__(NTHR, 1)
lstm_kernel(const float* __restrict__ Wih, const float* __restrict__ Whh,
            const float* __restrict__ h0c, const float* __restrict__ c0c,
            const float* __restrict__ hmask, const float* __restrict__ cmask,
            const float* __restrict__ labels, float* __restrict__ out,
            unsigned char* __restrict__ ws)
{
  const int tid = threadIdx.x, bid = blockIdx.x;
  const int L = bid & 1, g = bid >> 1;
  const int lane = tid & 63, w = tid >> 6;
  const int mt = w & 1, nt = (w >> 1) & 1, kh = w >> 2;
  const int q = lane >> 4, m0 = lane & 15;

  __shared__ __align__(16) unsigned short As[41 * 1032];   // 84.6 KB (rows 32..40 = pad -> 1 block/CU)
  __shared__ __align__(16) float Cred[2 * 32 * 36];        // 9.2 KB
  __shared__ __align__(16) float Hpart[32][33];            // 4.2 KB local h-GEMM partial

  unsigned short* HOUT = (unsigned short*)(ws + WS_HOUT);
  unsigned short* XIN  = (unsigned short*)(ws + WS_XIN);
  unsigned short* HIL  = (unsigned short*)(ws + (L ? WS_HI1 : WS_HI0));
  int*   flg = (int*)(ws + WS_FLG);
  const float* bcb = (const float*)(ws + WS_BCB);
  float* sse = (float*)(ws + WS_SSE);

  // ---- one-time: this layer's W_ih + W_hh rows -> bf16 registers (128 VGPRs) ----
  // wave-tile n = nt*16+m0 -> weight row = (n>>3)*1024 + g*8 + (n&7); K = kh*512 + q*8 + ks*32
  uint4 wx[16], wh[16];
  {
    const int nloc = nt * 16 + m0;
    const size_t wrow = (size_t)((nloc >> 3) * 1024 + g * 8 + (nloc & 7));
    const int kbase = kh * 512 + q * 8;
    const float* bx = Wih + (size_t)L * 4194304 + wrow * 1024 + kbase;
    const float* bh = Whh + (size_t)L * 4194304 + wrow * 1024 + kbase;
#pragma unroll
    for (int ks = 0; ks < 16; ++ks) {
      float4 a = *(const float4*)(bx + ks * 32), b = *(const float4*)(bx + ks * 32 + 4);
      wx[ks].x = (unsigned int)f2bf(a.x) | ((unsigned int)f2bf(a.y) << 16);
      wx[ks].y = (unsigned int)f2bf(a.z) | ((unsigned int)f2bf(a.w) << 16);
      wx[ks].z = (unsigned int)f2bf(b.x) | ((unsigned int)f2bf(b.y) << 16);
      wx[ks].w = (unsigned int)f2bf(b.z) | ((unsigned int)f2bf(b.w) << 16);
      float4 c = *(const float4*)(bh + ks * 32), d = *(const float4*)(bh + ks * 32 + 4);
      wh[ks].x = (unsigned int)f2bf(c.x) | ((unsigned int)f2bf(c.y) << 16);
      wh[ks].y = (unsigned int)f2bf(c.z) | ((unsigned int)f2bf(c.w) << 16);
      wh[ks].z = (unsigned int)f2bf(d.x) | ((unsigned int)f2bf(d.y) << 16);
      wh[ks].w = (unsigned int)f2bf(d.z) | ((unsigned int)f2bf(d.w) << 16);
    }
  }

  // ---- block-local pointwise state (tid<256: 1 batch-row x 1 column) ----
  const int m = tid >> 3, jc = tid & 7, col = g * 8 + jc;
  float cs = 0.f, hs = 0.f, bv[4] = {0.f, 0.f, 0.f, 0.f};
  if (tid < 256) {
    cs = c0c[L * 32768 + m * 1024 + col];
    hs = h0c[L * 32768 + m * 1024 + col];
#pragma unroll
    for (int gt = 0; gt < 4; ++gt) bv[gt] = bcb[L * 4096 + gt * 1024 + col];
  }

  // ---- priming shadow: h-GEMM for t=0 from initial h (no dependency) ----
  stage64k(HIL, As, tid);
  __syncthreads();
  gemm_to_cred(wh, As, Cred, mt, nt, kh, q, m0);
  __syncthreads();
  {
    const int idx = tid * 2, mh = idx >> 5, nh = idx & 31;
    Hpart[mh][nh]     = Cred[mh * 36 + nh]     + Cred[32 * 36 + mh * 36 + nh];
    Hpart[mh][nh + 1] = Cred[mh * 36 + nh + 1] + Cred[32 * 36 + mh * 36 + nh + 1];
  }

#pragma unroll 1
  for (int t = 0; t < 16; ++t) {
    const int ci = 2 * t + L;

    // prefetch masks/labels (immutable, cached; hides under poll)
    float hmv = 0.f, cmv = 0.f, lbv = 0.f;
    if (tid < 256) {
      const int mb = ci * 32768 + m * 1024 + col;
      hmv = hmask[mb]; cmv = cmask[mb];
      if (L == 1) lbv = labels[(m * 16 + t) * 1024 + col];
    }

    // ---- the ONE cross-block handoff: wait for cell ci-1 ----
    if (ci > 0 && tid < 128) {
      while (ald(&flg[((ci - 1) * 128 + tid) * 16]) < ci)
        __builtin_amdgcn_s_sleep(1);
    }
    __syncthreads();

    // stage x-input: h(ci-1) (or XIN for cell 0)
    const unsigned short* xsrc = (ci == 0)
        ? XIN
        : HOUT + (size_t)((L == 0) ? (2 + ((t - 1) & 1)) : (t & 1)) * 32768;
    stage64k(xsrc, As, tid);
    __syncthreads();

    // x-GEMM
    gemm_to_cred(wx, As, Cred, mt, nt, kh, q, m0);
    __syncthreads();

    // pointwise: gates = x-GEMM + local h-partial + bias
    if (tid < 256) {
      float ga[4];
#pragma unroll
      for (int gt = 0; gt < 4; ++gt)
        ga[gt] = Cred[m * 36 + gt * 8 + jc] + Cred[32 * 36 + m * 36 + gt * 8 + jc]
               + Hpart[m][gt * 8 + jc] + bv[gt];
      const float ii = sigf(ga[0]), ff = sigf(ga[1]);
      const float gv = tanhf(ga[2]), oo = sigf(ga[3]);
      const float cc = ff * cs + ii * gv;
      const float hc = oo * tanhf(cc);
      const float hn = hmv * hs + (1.0f - hmv) * hc;
      const float cn = cmv * cs + (1.0f - cmv) * cc;
      cs = cn; hs = hn;

      // publish h (single destination), packed pairs
      const float hnp = __shfl_xor(hn, 1);
      if (!(tid & 1)) {
        const unsigned int hb = (unsigned int)f2bf(hn) | ((unsigned int)f2bf(hnp) << 16);
        xst((unsigned int*)&HOUT[(size_t)(L * 2 + (t & 1)) * 32768 + m * 1024 + col], hb);
      }
      if (L == 1) {
        out[(m * 16 + t) * 1024 + col] = hn;      // d_out: flushed at kernel boundary
        float d = hn - lbv;
        float s = d * d;
#pragma unroll
        for (int off = 32; off > 0; off >>= 1) s += __shfl_down(s, off);
        if ((tid & 63) == 0) atomicAdd(sse, s);
      }
    }
    __syncthreads();                 // per-wave vmcnt(0): publishes drained
    if (tid == 0) xst(&flg[(ci * 128 + g) * 16], ci + 1);

    // ---- shadow (idle window): h-GEMM for next own-layer cell from h_L(t) ----
    if (t < 15) {
      if (tid < 128) {
        while (ald(&flg[(ci * 128 + tid) * 16]) < ci + 1)
          __builtin_amdgcn_s_sleep(1);
      }
      __syncthreads();
      stage64k(HOUT + (size_t)(L * 2 + (t & 1)) * 32768, As, tid);
      __syncthreads();
      gemm_to_cred(wh, As, Cred, mt, nt, kh, q, m0);
      __syncthreads();
      const int idx = tid * 2, mh = idx >> 5, nh = idx & 31;
      Hpart[mh][nh]     = Cred[mh * 36 + nh]     + Cred[32 * 36 + mh * 36 + nh];
      Hpart[mh][nh + 1] = Cred[mh * 36 + nh + 1] + Cred[32 * 36 + mh * 36 + nh + 1];
    }
  }
}

// ---------------- finalize: loss ----------------
__global__ void fin_kernel(float* __restrict__ out, unsigned char* __restrict__ ws) {
  if (blockIdx.x == 0 && threadIdx.x == 0)
    out[524288] = *(float*)(ws + WS_SSE) * (1.0f / 524288.0f);
}

extern "C" void kernel_launch(void* const* d_in, const int* in_sizes, int n_in,
                              void* d_out, int out_size, void* d_ws, size_t ws_size,
                              hipStream_t stream) {
  (void)in_sizes; (void)n_in; (void)out_size; (void)ws_size;
  const float* x   = (const float*)d_in[0];
  const float* h0  = (const float*)d_in[1];
  const float* c0  = (const float*)d_in[2];
  const float* hm  = (const float*)d_in[3];
  const float* cm  = (const float*)d_in[4];
  const float* lb  = (const float*)d_in[5];
  const float* wih = (const float*)d_in[6];
  const float* whh = (const float*)d_in[7];
  const float* bi  = (const float*)d_in[8];
  const float* bh  = (const float*)d_in[9];
  float* out = (float*)d_out;
  unsigned char* ws = (unsigned char*)d_ws;

  prep_kernel<<<dim3(256), dim3(256), 0, stream>>>(x, h0, bi, bh, ws);
  lstm_kernel<<<dim3(256), dim3(NTHR), 0, stream>>>(wih, whh, h0, c0, hm, cm, lb, out, ws);
  fin_kernel<<<dim3(1), dim3(64), 0, stream>>>(out, ws);
}